// Round 7
// baseline (5100.980 us; speedup 1.0000x reference)
//
#include <hip/hip_runtime.h>
#include <math.h>

namespace {

constexpr int kB = 512;
constexpr int kL = 128;
constexpr int kD = 128;
constexpr int kSteps = 126;   // L - 2

// ---- workspace layout (float offsets) ----
constexpr size_t OFF_W2IH = 0;          // [64][512][2] w_ih k-pair interleaved
constexpr size_t OFF_W2HH = 65536;      // [64][512][2] w_hh k-pair interleaved
constexpr size_t OFF_BIAS = 131072;     // [512] b_ih + b_hh
constexpr size_t OFF_WQL4 = 131584;     // [8][512][4] lane-matched wq_g for P3
constexpr size_t OFF_WIHT = 147968;     // [128][512] w_ih k-major (for prep_gx)
constexpr size_t OFF_WQTP = 213504;     // [128][128] wq_p k-major
constexpr size_t OFF_WRTG = 229888;     // [128][128] wr_g k-major
constexpr size_t OFF_WRTP = 246272;     // [128][128] wr_p k-major
constexpr size_t OFF_REFG = 262656;                                 // [L][B][D]
constexpr size_t OFF_REFP = OFF_REFG + (size_t)kL * kB * kD;
constexpr size_t OFF_ENCQ = OFF_REFP + (size_t)kL * kB * kD;        // enc@wq_p^T + bq_p
constexpr size_t kTotalNoGx = OFF_ENCQ + (size_t)kL * kB * kD;
constexpr size_t OFF_GX   = kTotalNoGx;                             // [129*512][512]
constexpr size_t kTotalGx = OFF_GX + (size_t)129 * kB * 512;        // ~237 MB

constexpr size_t OUT_IDX_OFF = (size_t)kSteps * kB * kL;  // probs first, then idx

// ---- static LDS layout (float offsets), ~8.2 KB ----
constexpr int SM_H   = 0;     // [128]
constexpr int SM_C   = 128;   // [128]
constexpr int SM_G   = 256;   // [512] gates
constexpr int SM_RED = 768;   // [512] P6' partials / x-stage (fallback)
constexpr int SM_QG  = 1280;  // [128]
constexpr int SM_U   = 1408;  // [128]
constexpr int SM_PG  = 1536;  // [128] glimpse probs
constexpr int SM_M   = 1664;  // [128] mask
constexpr int SM_VG  = 1792;  // [128]
constexpr int SM_VP  = 1920;  // [128]
constexpr int SM_IDX = 2048;  // int
constexpr int SM_TOTAL = 2052;

// fast transcendentals: v_exp_f32-based, ~2 ulp, branch-free, inf-safe
__device__ __forceinline__ float tanh_fast(float x) {
  return 1.0f - __fdividef(2.0f, __expf(2.0f * x) + 1.0f);
}
__device__ __forceinline__ float sig_fast(float x) {
  return __fdividef(1.0f, 1.0f + __expf(-x));
}

} // namespace

// ---------- one-time: weight relayouts + fused bias ----------
extern "C" __global__ void prep_weights(
    const float* __restrict__ w_ih, const float* __restrict__ w_hh,
    const float* __restrict__ b_ih, const float* __restrict__ b_hh,
    const float* __restrict__ wq_p, const float* __restrict__ wq_g,
    const float* __restrict__ wr_p, const float* __restrict__ wr_g,
    float* __restrict__ ws) {
  const int tid = blockIdx.x * blockDim.x + threadIdx.x;
  const int nth = gridDim.x * blockDim.x;
  // k-pair interleaved: W2[(k2*512+g)*2+p] = w[g][2*k2+p]
  for (int i = tid; i < 64 * 512 * 2; i += nth) {
    const int k2 = i >> 10, rem = i & 1023, g = rem >> 1, p = rem & 1;
    const int k = 2 * k2 + p;
    ws[OFF_W2IH + i] = w_ih[g * 128 + k];
    ws[OFF_W2HH + i] = w_hh[g * 128 + k];
  }
  for (int i = tid; i < 512; i += nth) ws[OFF_BIAS + i] = b_ih[i] + b_hh[i];
  // WQL4[kk4][t][e] = wq_g[t>>2][(t&3)*32 + kk4*4 + e]
  for (int i = tid; i < 16384; i += nth) {
    const int e = i & 3, r = i >> 2;
    const int t = r & 511, kk4 = r >> 9;
    const int j = t >> 2, kq = t & 3;
    ws[OFF_WQL4 + i] = wq_g[j * 128 + kq * 32 + kk4 * 4 + e];
  }
  // w_ih k-major [k][512] for prep_gx
  for (int i = tid; i < 128 * 512; i += nth) {
    const int k = i >> 9, g = i & 511;
    ws[OFF_WIHT + i] = w_ih[g * 128 + k];
  }
  // k-major 128x128 transposes for prep_mm
  for (int i = tid; i < 128 * 128; i += nth) {
    const int k = i >> 7, j = i & 127;
    ws[OFF_WQTP + i] = wq_p[j * 128 + k];
    ws[OFF_WRTG + i] = wr_g[j * 128 + k];
    ws[OFF_WRTP + i] = wr_p[j * 128 + k];
  }
}

// ---------- one-time tiled GEMM: {ref_g, ref_p, encq} = enc @ W + bias ----------
extern "C" __global__ __launch_bounds__(256) void prep_mm(
    const float* __restrict__ enc,
    const float* __restrict__ br_g, const float* __restrict__ br_p,
    const float* __restrict__ bq_p,
    float* __restrict__ ws) {
  extern __shared__ float lds[];
  float* wT = lds;          // [128 k][128 j]
  float* sx = lds + 16384;  // [64 r][128 k]
  const int t = threadIdx.x;
  const int table = blockIdx.y;
  const size_t wOff = (table == 0) ? OFF_WRTG : (table == 1) ? OFF_WRTP : OFF_WQTP;
  const size_t oOff = (table == 0) ? OFF_REFG : (table == 1) ? OFF_REFP : OFF_ENCQ;
  const float* bias = (table == 0) ? br_g : (table == 1) ? br_p : bq_p;
  for (int i = t; i < 16384; i += 256) wT[i] = ws[wOff + i];
  const size_t r0 = (size_t)blockIdx.x * 64;
  for (int i = t; i < 8192; i += 256) sx[i] = enc[r0 * 128 + i];
  __syncthreads();
  const int j0 = (t & 31) * 4, rg = t >> 5;
  float4 acc[8];
  const float4 b4 = *(const float4*)(bias + j0);
  #pragma unroll
  for (int r = 0; r < 8; ++r) acc[r] = b4;
  for (int k4 = 0; k4 < 32; ++k4) {
    const float4 w0 = *(const float4*)&wT[(k4 * 4 + 0) * 128 + j0];
    const float4 w1 = *(const float4*)&wT[(k4 * 4 + 1) * 128 + j0];
    const float4 w2 = *(const float4*)&wT[(k4 * 4 + 2) * 128 + j0];
    const float4 w3 = *(const float4*)&wT[(k4 * 4 + 3) * 128 + j0];
    #pragma unroll
    for (int r = 0; r < 8; ++r) {
      const float4 xv = *(const float4*)&sx[(rg * 8 + r) * 128 + k4 * 4];
      acc[r].x += xv.x * w0.x + xv.y * w1.x + xv.z * w2.x + xv.w * w3.x;
      acc[r].y += xv.x * w0.y + xv.y * w1.y + xv.z * w2.y + xv.w * w3.y;
      acc[r].z += xv.x * w0.z + xv.y * w1.z + xv.z * w2.z + xv.w * w3.z;
      acc[r].w += xv.x * w0.w + xv.y * w1.w + xv.z * w2.w + xv.w * w3.w;
    }
  }
  #pragma unroll
  for (int r = 0; r < 8; ++r) {
    *(float4*)&ws[oOff + (r0 + rg * 8 + r) * 128 + j0] = acc[r];
  }
}

// ---------- one-time tiled GEMM: gx[rid][g] = x_rid . w_ih[g,:] + bias[g] ----------
extern "C" __global__ __launch_bounds__(256) void prep_gx(
    const float* __restrict__ emb, const float* __restrict__ dec0,
    float* __restrict__ ws) {
  extern __shared__ float lds[];
  float* wT = lds;          // [128 k][128 g]
  float* sx = lds + 16384;  // [64 r][128 k]
  const int t = threadIdx.x;
  const int g0 = blockIdx.y * 128;
  for (int i = t; i < 16384; i += 256) {
    wT[i] = ws[OFF_WIHT + (size_t)(i >> 7) * 512 + g0 + (i & 127)];
  }
  const size_t r0 = (size_t)blockIdx.x * 64;
  for (int i = t; i < 8192; i += 256) {
    const size_t rid = r0 + (i >> 7);
    const int c = i & 127;
    sx[i] = (rid < 65536) ? emb[rid * 128 + c] : dec0[(rid - 65536) * 128 + c];
  }
  __syncthreads();
  const int j0 = (t & 31) * 4, rg = t >> 5;
  float4 acc[8];
  const float4 b4 = *(const float4*)(ws + OFF_BIAS + g0 + j0);
  #pragma unroll
  for (int r = 0; r < 8; ++r) acc[r] = b4;
  for (int k4 = 0; k4 < 32; ++k4) {
    const float4 w0 = *(const float4*)&wT[(k4 * 4 + 0) * 128 + j0];
    const float4 w1 = *(const float4*)&wT[(k4 * 4 + 1) * 128 + j0];
    const float4 w2 = *(const float4*)&wT[(k4 * 4 + 2) * 128 + j0];
    const float4 w3 = *(const float4*)&wT[(k4 * 4 + 3) * 128 + j0];
    #pragma unroll
    for (int r = 0; r < 8; ++r) {
      const float4 xv = *(const float4*)&sx[(rg * 8 + r) * 128 + k4 * 4];
      acc[r].x += xv.x * w0.x + xv.y * w1.x + xv.z * w2.x + xv.w * w3.x;
      acc[r].y += xv.x * w0.y + xv.y * w1.y + xv.z * w2.y + xv.w * w3.y;
      acc[r].z += xv.x * w0.z + xv.y * w1.z + xv.z * w2.z + xv.w * w3.z;
      acc[r].w += xv.x * w0.w + xv.y * w1.w + xv.z * w2.w + xv.w * w3.w;
    }
  }
  #pragma unroll
  for (int r = 0; r < 8; ++r) {
    *(float4*)&ws[OFF_GX + (r0 + rg * 8 + r) * 512 + g0 + j0] = acc[r];
  }
}

// ---------- persistent decode: 512 threads per batch element, 2 blocks/CU, 16 waves/CU ----------
template <bool GX>
__global__ __launch_bounds__(512, 4) void decode_main(
    const float* __restrict__ dec0, const float* __restrict__ emb,
    const float* __restrict__ h0,   const float* __restrict__ c0,
    const float* __restrict__ bq_g, const float* __restrict__ v_p,
    const float* __restrict__ v_g,
    const float* __restrict__ ws, float* __restrict__ out) {
  __shared__ float sm[SM_TOTAL];
  int* s_idx = (int*)(sm + SM_IDX);

  const int t = threadIdx.x;
  const int b = blockIdx.x;
  const int wv = t >> 6;                 // 0..7
  const int rr = (t >> 4) & 3;           // row-in-group
  const int sub = t & 15;                // dim-16th
  const int dd = t & 127, lq = t >> 7;   // P6' mapping

  const float* REFG = ws + OFF_REFG;
  const float* REFP = ws + OFF_REFP;
  const float* ENCQ = ws + OFF_ENCQ;
  const float* GXT  = ws + OFF_GX;
  const float* W2IH = ws + OFF_W2IH + 2 * t;
  const float* W2HH = ws + OFF_W2HH + 2 * t;
  const float* WQL  = ws + OFF_WQL4 + 4 * t;

  const float bias_t = ws[OFF_BIAS + t];
  const float bqg = bq_g[t >> 2];

  if (t < 128) {
    sm[SM_H + t]  = h0[b * 128 + t];
    sm[SM_C + t]  = c0[b * 128 + t];
    sm[SM_M + t]  = (t < 2) ? 1.f : 0.f;   // indices 0,1 pre-visited
    sm[SM_VG + t] = v_g[t];
    sm[SM_VP + t] = v_p[t];
  }
  if (t == 0) *s_idx = 128;   // sentinel: dec0 row
  __syncthreads();

  for (int step = 0; step < kSteps; ++step) {
    const int row = *s_idx;
    // ---- P1: gate t = gx[row] (or bias + W_ih.x) + W_hh.h ----
    {
      float a;
      if constexpr (GX) {
        a = GXT[((size_t)row * kB + b) * 512 + t];
      } else {
        if (t < 128) {
          const float* xs = (row == 128) ? dec0 + (size_t)b * 128
                                         : emb + ((size_t)row * kB + b) * kD;
          sm[SM_RED + t] = xs[t];
        }
        __syncthreads();
        a = bias_t;
        #pragma unroll 8
        for (int k2 = 0; k2 < 64; ++k2) {
          const float2 w  = *(const float2*)(W2IH + (size_t)k2 * 1024);
          const float2 x2 = *(const float2*)&sm[SM_RED + 2 * k2];
          a += w.x * x2.x + w.y * x2.y;
        }
      }
      #pragma unroll 8
      for (int k2 = 0; k2 < 64; ++k2) {
        const float2 w  = *(const float2*)(W2HH + (size_t)k2 * 1024);
        const float2 h2 = *(const float2*)&sm[SM_H + 2 * k2];
        a += w.x * h2.x + w.y * h2.y;
      }
      sm[SM_G + t] = a;
    }
    __syncthreads();  // B1
    // ---- P2: LSTM cell (t<128); mask update (use_prev only) ----
    if (t < 128) {
      const float gi = sm[SM_G + t];
      const float gf = sm[SM_G + 128 + t];
      const float gg = sm[SM_G + 256 + t];
      const float go = sm[SM_G + 384 + t];
      const float cc = sig_fast(gf) * sm[SM_C + t] + sig_fast(gi) * tanh_fast(gg);
      sm[SM_C + t] = cc;
      sm[SM_H + t] = sig_fast(go) * tanh_fast(cc);
    } else if (t == 128 && step > 0) {
      sm[SM_M + row] = 1.f;
    }
    __syncthreads();  // B2
    // ---- P3: q_g[j] = h . wq_g[j] + bq_g (4-thread k-split, shfl-folded) ----
    {
      const int kq = t & 3;
      float acc = 0.f;
      #pragma unroll
      for (int kk4 = 0; kk4 < 8; ++kk4) {
        const float4 w  = *(const float4*)(WQL + (size_t)kk4 * 2048);
        const float4 h4 = *(const float4*)&sm[SM_H + kq * 32 + kk4 * 4];
        acc += h4.x * w.x + h4.y * w.y + h4.z * w.z + h4.w * w.w;
      }
      acc += __shfl_xor(acc, 1);
      acc += __shfl_xor(acc, 2);
      if (kq == 0) sm[SM_QG + (t >> 2)] = acc + bqg;
    }
    __syncthreads();  // B3
    // ---- P4: glimpse scores u[l] = v_g . tanh(ref_g + q_g), ref_g streamed ----
    {
      const float4 qa = *(const float4*)&sm[SM_QG + sub * 8];
      const float4 qb = *(const float4*)&sm[SM_QG + sub * 8 + 4];
      const float4 va = *(const float4*)&sm[SM_VG + sub * 8];
      const float4 vb = *(const float4*)&sm[SM_VG + sub * 8 + 4];
      #pragma unroll
      for (int it = 0; it < 4; ++it) {
        const int l = it * 32 + wv * 4 + rr;
        const float* rg = REFG + ((size_t)l * kB + b) * kD + sub * 8;
        const float4 ra = *(const float4*)rg;
        const float4 rb = *(const float4*)(rg + 4);
        float s;
        s  = va.x * tanh_fast(ra.x + qa.x);
        s += va.y * tanh_fast(ra.y + qa.y);
        s += va.z * tanh_fast(ra.z + qa.z);
        s += va.w * tanh_fast(ra.w + qa.w);
        s += vb.x * tanh_fast(rb.x + qb.x);
        s += vb.y * tanh_fast(rb.y + qb.y);
        s += vb.z * tanh_fast(rb.z + qb.z);
        s += vb.w * tanh_fast(rb.w + qb.w);
        s += __shfl_xor(s, 1); s += __shfl_xor(s, 2);
        s += __shfl_xor(s, 4); s += __shfl_xor(s, 8);
        if (sub == 0) {
          if (step > 0 && sm[SM_M + l] != 0.f) s = -INFINITY;
          sm[SM_U + l] = s;
        }
      }
    }
    __syncthreads();  // B4
    // ---- P5: glimpse softmax (wave 0) -> PG ----
    if (t < 64) {
      const float v0 = sm[SM_U + t], v1 = sm[SM_U + 64 + t];
      float m = fmaxf(v0, v1);
      #pragma unroll
      for (int off = 1; off < 64; off <<= 1) m = fmaxf(m, __shfl_xor(m, off, 64));
      const float e0 = __expf(v0 - m), e1 = __expf(v1 - m);
      float ssum = e0 + e1;
      #pragma unroll
      for (int off = 1; off < 64; off <<= 1) ssum += __shfl_xor(ssum, off, 64);
      const float inv = __fdividef(1.0f, ssum);
      sm[SM_PG + t]      = e0 * inv;
      sm[SM_PG + 64 + t] = e1 * inv;
    }
    __syncthreads();  // B5
    // ---- P6': q_p partials over l-quarters: RED[lq*128+dd] = sum p[l]*encq[l][dd] ----
    {
      float acc = 0.f;
      #pragma unroll 8
      for (int ll = 0; ll < 32; ++ll) {
        const int l = lq * 32 + ll;
        acc += sm[SM_PG + l] * ENCQ[((size_t)l * kB + b) * kD + dd];
      }
      sm[SM_RED + lq * 128 + dd] = acc;
    }
    __syncthreads();  // B6
    // ---- P8: fold q_p; pointer scores from streamed ref_p; 10*tanh clip; mask ----
    {
      const float4 q0a = *(const float4*)&sm[SM_RED + sub * 8];
      const float4 q0b = *(const float4*)&sm[SM_RED + sub * 8 + 4];
      const float4 q1a = *(const float4*)&sm[SM_RED + 128 + sub * 8];
      const float4 q1b = *(const float4*)&sm[SM_RED + 128 + sub * 8 + 4];
      const float4 q2a = *(const float4*)&sm[SM_RED + 256 + sub * 8];
      const float4 q2b = *(const float4*)&sm[SM_RED + 256 + sub * 8 + 4];
      const float4 q3a = *(const float4*)&sm[SM_RED + 384 + sub * 8];
      const float4 q3b = *(const float4*)&sm[SM_RED + 384 + sub * 8 + 4];
      const float4 qa = make_float4(q0a.x + q1a.x + q2a.x + q3a.x,
                                    q0a.y + q1a.y + q2a.y + q3a.y,
                                    q0a.z + q1a.z + q2a.z + q3a.z,
                                    q0a.w + q1a.w + q2a.w + q3a.w);
      const float4 qb = make_float4(q0b.x + q1b.x + q2b.x + q3b.x,
                                    q0b.y + q1b.y + q2b.y + q3b.y,
                                    q0b.z + q1b.z + q2b.z + q3b.z,
                                    q0b.w + q1b.w + q2b.w + q3b.w);
      const float4 va = *(const float4*)&sm[SM_VP + sub * 8];
      const float4 vb = *(const float4*)&sm[SM_VP + sub * 8 + 4];
      #pragma unroll
      for (int it = 0; it < 4; ++it) {
        const int l = it * 32 + wv * 4 + rr;
        const float* rp = REFP + ((size_t)l * kB + b) * kD + sub * 8;
        const float4 ra = *(const float4*)rp;
        const float4 rb = *(const float4*)(rp + 4);
        float s;
        s  = va.x * tanh_fast(ra.x + qa.x);
        s += va.y * tanh_fast(ra.y + qa.y);
        s += va.z * tanh_fast(ra.z + qa.z);
        s += va.w * tanh_fast(ra.w + qa.w);
        s += vb.x * tanh_fast(rb.x + qb.x);
        s += vb.y * tanh_fast(rb.y + qb.y);
        s += vb.z * tanh_fast(rb.z + qb.z);
        s += vb.w * tanh_fast(rb.w + qb.w);
        s += __shfl_xor(s, 1); s += __shfl_xor(s, 2);
        s += __shfl_xor(s, 4); s += __shfl_xor(s, 8);
        if (sub == 0) {
          float uu = 10.f * tanh_fast(s);
          if (step > 0 && sm[SM_M + l] != 0.f) uu = -INFINITY;
          sm[SM_U + l] = uu;
        }
      }
    }
    __syncthreads();  // B7
    // ---- P9: pointer softmax + first-index argmax; write probs + idx ----
    if (t < 64) {
      const float v0 = sm[SM_U + t], v1 = sm[SM_U + 64 + t];
      float m = fmaxf(v0, v1);
      #pragma unroll
      for (int off = 1; off < 64; off <<= 1) m = fmaxf(m, __shfl_xor(m, off, 64));
      const float e0 = __expf(v0 - m), e1 = __expf(v1 - m);
      float ssum = e0 + e1;
      #pragma unroll
      for (int off = 1; off < 64; off <<= 1) ssum += __shfl_xor(ssum, off, 64);
      const float inv = __fdividef(1.0f, ssum);
      float* orow = out + ((size_t)step * kB + b) * kL;
      orow[t]      = e0 * inv;
      orow[64 + t] = e1 * inv;
      float av; int ai;
      if (v0 >= v1) { av = v0; ai = t; } else { av = v1; ai = t + 64; }
      #pragma unroll
      for (int off = 1; off < 64; off <<= 1) {
        const float ov = __shfl_xor(av, off, 64);
        const int   oi = __shfl_xor(ai, off, 64);
        if (ov > av || (ov == av && oi < ai)) { av = ov; ai = oi; }
      }
      if (t == 0) {
        *s_idx = ai;
        out[OUT_IDX_OFF + (size_t)step * kB + b] = (float)ai;
      }
    }
    __syncthreads();  // B8
  }
}

extern "C" void kernel_launch(void* const* d_in, const int* in_sizes, int n_in,
                              void* d_out, int out_size, void* d_ws, size_t ws_size,
                              hipStream_t stream) {
  (void)in_sizes; (void)n_in; (void)out_size;
  const float* dec0 = (const float*)d_in[0];
  const float* emb  = (const float*)d_in[1];
  const float* h0   = (const float*)d_in[2];
  const float* c0   = (const float*)d_in[3];
  const float* enc  = (const float*)d_in[4];
  const float* w_ih = (const float*)d_in[5];
  const float* w_hh = (const float*)d_in[6];
  const float* b_ih = (const float*)d_in[7];
  const float* b_hh = (const float*)d_in[8];
  const float* wq_p = (const float*)d_in[9];
  const float* bq_p = (const float*)d_in[10];
  const float* wr_p = (const float*)d_in[11];
  const float* br_p = (const float*)d_in[12];
  const float* v_p  = (const float*)d_in[13];
  const float* wq_g = (const float*)d_in[14];
  const float* bq_g = (const float*)d_in[15];
  const float* wr_g = (const float*)d_in[16];
  const float* br_g = (const float*)d_in[17];
  const float* v_g  = (const float*)d_in[18];
  float* ws  = (float*)d_ws;
  float* out = (float*)d_out;

  const bool gx_ok = ws_size >= kTotalGx * 4;   // ~237 MB with the gx table

  prep_weights<<<dim3(64), dim3(256), 0, stream>>>(
      w_ih, w_hh, b_ih, b_hh, wq_p, wq_g, wr_p, wr_g, ws);
  prep_mm<<<dim3(1024, 3), dim3(256), 24576 * 4, stream>>>(
      enc, br_g, br_p, bq_p, ws);
  if (gx_ok) {
    prep_gx<<<dim3(1032, 4), dim3(256), 24576 * 4, stream>>>(emb, dec0, ws);
    decode_main<true><<<dim3(512), dim3(512), 0, stream>>>(
        dec0, emb, h0, c0, bq_g, v_p, v_g, ws, out);
  } else {
    decode_main<false><<<dim3(512), dim3(512), 0, stream>>>(
        dec0, emb, h0, c0, bq_g, v_p, v_g, ws, out);
  }
}